// Round 2
// baseline (1083.591 us; speedup 1.0000x reference)
//
#include <hip/hip_runtime.h>
#include <hip/hip_bf16.h>
#include <cstdint>

#define T_TOK 2048
#define HD 2048
#define ID 1408
#define NE 16
#define TOPK 6

#define BM 128
#define BN 64
#define BK 64

typedef __bf16 bf16x8 __attribute__((ext_vector_type(8)));
typedef float f32x4 __attribute__((ext_vector_type(4)));

typedef const __attribute__((address_space(1))) void* gas1_t;
typedef __attribute__((address_space(3))) void* las3_t;
#define GLDS16(g, l) __builtin_amdgcn_global_load_lds((gas1_t)(g), (las3_t)(l), 16, 0, 0)

__device__ __forceinline__ void barrier_sync() {
    asm volatile("" ::: "memory");
    __builtin_amdgcn_s_barrier();
    asm volatile("" ::: "memory");
}
#define WAITV(N) asm volatile("s_waitcnt vmcnt(" #N ")" ::: "memory")
#define WAITL0   asm volatile("s_waitcnt lgkmcnt(0)" ::: "memory")

// --- small kernels -----------------------------------------------------

__global__ void k_combine(const int* __restrict__ idx, const float* __restrict__ w,
                          float* __restrict__ combine) {
    int t = blockIdx.x * blockDim.x + threadIdx.x;
    if (t >= T_TOK) return;
    int ie[TOPK];
    float fw[TOPK];
#pragma unroll
    for (int k = 0; k < TOPK; k++) { ie[k] = idx[t * TOPK + k]; fw[k] = w[t * TOPK + k]; }
#pragma unroll
    for (int e = 0; e < NE; e++) {
        float s = 0.f;
#pragma unroll
        for (int k = 0; k < TOPK; k++) if (ie[k] == e) s += fw[k];
        combine[t * NE + e] = s;
    }
}

__global__ void k_lists(const float* __restrict__ combine, int* __restrict__ counts,
                        int* __restrict__ tok, float* __restrict__ wts) {
    int t = blockIdx.x * blockDim.x + threadIdx.x;
    if (t >= T_TOK) return;
    for (int e = 0; e < NE; e++) {
        float c = combine[t * NE + e];
        if (c != 0.0f) {
            int p = atomicAdd(&counts[e], 1);
            tok[e * T_TOK + p] = t;
            wts[e * T_TOK + p] = c;
        }
    }
}

__global__ void k_cvt(const float* __restrict__ x, __bf16* __restrict__ xb) {
    int i = (blockIdx.x * 256 + threadIdx.x) * 8;
    float4 a = *(const float4*)(x + i);
    float4 b = *(const float4*)(x + i + 4);
    bf16x8 o;
    o[0] = (__bf16)a.x; o[1] = (__bf16)a.y; o[2] = (__bf16)a.z; o[3] = (__bf16)a.w;
    o[4] = (__bf16)b.x; o[5] = (__bf16)b.y; o[6] = (__bf16)b.z; o[7] = (__bf16)b.w;
    *(bf16x8*)(xb + i) = o;
}

// --- LDS helpers -------------------------------------------------------

__device__ __forceinline__ int swz(int row, int cb) {
    return row * 128 + (cb ^ ((row & 7) << 4));
}

__device__ __forceinline__ bf16x8 ldfrag(const __bf16* base, int row, int cb) {
    return *(const bf16x8*)((const char*)base + swz(row, cb));
}

__device__ __forceinline__ void writeB16(char* lds, int row, int cbBase,
                                         float4 f0, float4 f1, float4 f2, float4 f3) {
    bf16x8 lo, hi;
    lo[0] = (__bf16)f0.x; lo[1] = (__bf16)f0.y; lo[2] = (__bf16)f0.z; lo[3] = (__bf16)f0.w;
    lo[4] = (__bf16)f1.x; lo[5] = (__bf16)f1.y; lo[6] = (__bf16)f1.z; lo[7] = (__bf16)f1.w;
    hi[0] = (__bf16)f2.x; hi[1] = (__bf16)f2.y; hi[2] = (__bf16)f2.z; hi[3] = (__bf16)f2.w;
    hi[4] = (__bf16)f3.x; hi[5] = (__bf16)f3.y; hi[6] = (__bf16)f3.z; hi[7] = (__bf16)f3.w;
    *(bf16x8*)(lds + swz(row, cbBase)) = lo;
    *(bf16x8*)(lds + swz(row, cbBase + 16)) = hi;
}

// --- GEMM1: act = silu(X@Gg^T) * (X@Gu^T)  ------------------------------

__global__ __launch_bounds__(256) void k_gemm1(
    const __bf16* __restrict__ Xb, const float* __restrict__ gup,
    const int* __restrict__ counts, const int* __restrict__ tok,
    __bf16* __restrict__ act) {
    int e = blockIdx.z;
    int cnt = counts[e];
    int m0 = blockIdx.x * BM;          // m innermost for weight-tile L2/L3 reuse
    if (m0 >= cnt) return;
    int n0 = blockIdx.y * BN;

    __shared__ __align__(16) __bf16 sA[2][BM * BK];
    __shared__ __align__(16) __bf16 sBg[BN * BK];
    __shared__ __align__(16) __bf16 sBu[BN * BK];
    __shared__ int tokLds[BM];

    int tid = threadIdx.x;
    if (tid < BM) {
        int g = m0 + tid;
        tokLds[tid] = (g < cnt) ? tok[e * T_TOK + g] : tok[e * T_TOK];
    }
    __syncthreads();

    int lane = tid & 63;
    int wid = tid >> 6;

    // A staging: wave w owns rows [32w, 32w+32), 4 glds calls x 8 rows x 128B.
    // Linear LDS dest; per-lane global source pre-swizzled so swizzled reads work.
    const __bf16* pA[4];
    int csw = ((lane & 7) ^ ((lane >> 3) & 7)) * 8;
#pragma unroll
    for (int j = 0; j < 4; j++) {
        int r = 32 * wid + 8 * j + (lane >> 3);
        pA[j] = Xb + (size_t)tokLds[r] * HD + csw;
    }

    // B: thread stages row br, 16-float chunk bc (for gate and up)
    int br = tid >> 2, bc = tid & 3;
    const float* gbase = gup + (size_t)e * (2 * ID) * HD;
    const float* bgSrc = gbase + (size_t)(n0 + br) * HD + bc * 16;
    const float* buSrc = gbase + (size_t)(ID + n0 + br) * HD + bc * 16;

    int wm = wid >> 1, wn = wid & 1;
    int l15 = lane & 15, lh = lane >> 4;

    f32x4 accg[4][2] = {};
    f32x4 accu[4][2] = {};

    // prologue: issue tile 0 (B -> regs, A -> sA[0])
    float4 g0 = ((const float4*)bgSrc)[0], g1 = ((const float4*)bgSrc)[1];
    float4 g2 = ((const float4*)bgSrc)[2], g3 = ((const float4*)bgSrc)[3];
    float4 u0 = ((const float4*)buSrc)[0], u1 = ((const float4*)buSrc)[1];
    float4 u2 = ((const float4*)buSrc)[2], u3 = ((const float4*)buSrc)[3];
#pragma unroll
    for (int j = 0; j < 4; j++)
        GLDS16(pA[j], &sA[0][(32 * wid + 8 * j) * BK]);

    const int NT = HD / BK;
    for (int k = 0; k < NT; k++) {
        int cur = k & 1;
        // write phase: cvt + ds_write B(k) (compiler auto-waits the reg deps)
        writeB16((char*)sBg, br, bc * 32, g0, g1, g2, g3);
        writeB16((char*)sBu, br, bc * 32, u0, u1, u2, u3);
        // prefetch tile k+1; keep it in flight across barriers (counted vmcnt)
        if (k + 1 < NT) {
            int k0 = (k + 1) * BK;
            const float* bg = bgSrc + k0;
            const float* bu = buSrc + k0;
            g0 = ((const float4*)bg)[0]; g1 = ((const float4*)bg)[1];
            g2 = ((const float4*)bg)[2]; g3 = ((const float4*)bg)[3];
            u0 = ((const float4*)bu)[0]; u1 = ((const float4*)bu)[1];
            u2 = ((const float4*)bu)[2]; u3 = ((const float4*)bu)[3];
#pragma unroll
            for (int j = 0; j < 4; j++)
                GLDS16(pA[j] + k0, &sA[cur ^ 1][(32 * wid + 8 * j) * BK]);
            WAITV(12);                 // tile-k glds (older) complete; 12 newest stay in flight
        } else {
            WAITV(0);
        }
        WAITL0;
        barrier_sync();                // tile k fully visible
        const __bf16* sAc = sA[cur];
#pragma unroll
        for (int kk = 0; kk < 2; kk++) {
            int cb = kk * 64 + lh * 16;
            bf16x8 a[4];
#pragma unroll
            for (int fm = 0; fm < 4; fm++)
                a[fm] = ldfrag(sAc, wm * 64 + fm * 16 + l15, cb);
#pragma unroll
            for (int fn = 0; fn < 2; fn++) {
                bf16x8 bg = ldfrag(sBg, wn * 32 + fn * 16 + l15, cb);
                bf16x8 bu = ldfrag(sBu, wn * 32 + fn * 16 + l15, cb);
#pragma unroll
                for (int fm = 0; fm < 4; fm++) {
                    accg[fm][fn] = __builtin_amdgcn_mfma_f32_16x16x32_bf16(a[fm], bg, accg[fm][fn], 0, 0, 0);
                    accu[fm][fn] = __builtin_amdgcn_mfma_f32_16x16x32_bf16(a[fm], bu, accu[fm][fn], 0, 0, 0);
                }
            }
        }
        barrier_sync();                // readers done before next overwrite
    }

    // epilogue: silu(gate)*up -> act (bf16)
#pragma unroll
    for (int fm = 0; fm < 4; fm++) {
#pragma unroll
        for (int fn = 0; fn < 2; fn++) {
#pragma unroll
            for (int j = 0; j < 4; j++) {
                int mloc = wm * 64 + fm * 16 + lh * 4 + j;
                int g = m0 + mloc;
                if (g < cnt) {
                    float gv = accg[fm][fn][j];
                    float uv = accu[fm][fn][j];
                    float sv = gv * (1.0f / (1.0f + __expf(-gv)));
                    int n = n0 + wn * 32 + fn * 16 + l15;
                    act[((size_t)e * T_TOK + g) * ID + n] = (__bf16)(sv * uv);
                }
            }
        }
    }
}

// --- GEMM2: out[tok] += (act @ Dn^T) * wt  (fp32 atomic scatter) --------

__global__ __launch_bounds__(256) void k_gemm2(
    const __bf16* __restrict__ act, const float* __restrict__ dn,
    const int* __restrict__ counts, const int* __restrict__ tok,
    const float* __restrict__ wts, float* __restrict__ out) {
    int e = blockIdx.z;
    int cnt = counts[e];
    int m0 = blockIdx.x * BM;
    if (m0 >= cnt) return;
    int n0 = blockIdx.y * BN;

    __shared__ __align__(16) __bf16 sA[2][BM * BK];
    __shared__ __align__(16) __bf16 sB[BN * BK];
    __shared__ int tokLds[BM];
    __shared__ float wtLds[BM];

    int tid = threadIdx.x;
    if (tid < BM) {
        int g = m0 + tid;
        bool v = g < cnt;
        tokLds[tid] = v ? tok[e * T_TOK + g] : 0;
        wtLds[tid] = v ? wts[e * T_TOK + g] : 0.f;
    }
    __syncthreads();

    int lane = tid & 63;
    int wid = tid >> 6;

    const __bf16* pA[4];
    int csw = ((lane & 7) ^ ((lane >> 3) & 7)) * 8;
#pragma unroll
    for (int j = 0; j < 4; j++) {
        int r = 32 * wid + 8 * j + (lane >> 3);
        pA[j] = act + ((size_t)e * T_TOK + m0 + r) * ID + csw;
    }

    int br = tid >> 2, bc = tid & 3;
    const float* bSrc = dn + (size_t)e * HD * ID + (size_t)(n0 + br) * ID + bc * 16;

    int wm = wid >> 1, wn = wid & 1;
    int l15 = lane & 15, lh = lane >> 4;

    f32x4 acc[4][2] = {};

    float4 b0 = ((const float4*)bSrc)[0], b1 = ((const float4*)bSrc)[1];
    float4 b2 = ((const float4*)bSrc)[2], b3 = ((const float4*)bSrc)[3];
#pragma unroll
    for (int j = 0; j < 4; j++)
        GLDS16(pA[j], &sA[0][(32 * wid + 8 * j) * BK]);

    const int NT = ID / BK;
    for (int k = 0; k < NT; k++) {
        int cur = k & 1;
        writeB16((char*)sB, br, bc * 32, b0, b1, b2, b3);
        if (k + 1 < NT) {
            int k0 = (k + 1) * BK;
            const float* bs = bSrc + k0;
            b0 = ((const float4*)bs)[0]; b1 = ((const float4*)bs)[1];
            b2 = ((const float4*)bs)[2]; b3 = ((const float4*)bs)[3];
#pragma unroll
            for (int j = 0; j < 4; j++)
                GLDS16(pA[j] + k0, &sA[cur ^ 1][(32 * wid + 8 * j) * BK]);
            WAITV(8);
        } else {
            WAITV(0);
        }
        WAITL0;
        barrier_sync();
        const __bf16* sAc = sA[cur];
#pragma unroll
        for (int kk = 0; kk < 2; kk++) {
            int cb = kk * 64 + lh * 16;
            bf16x8 a[4];
#pragma unroll
            for (int fm = 0; fm < 4; fm++)
                a[fm] = ldfrag(sAc, wm * 64 + fm * 16 + l15, cb);
#pragma unroll
            for (int fn = 0; fn < 2; fn++) {
                bf16x8 b = ldfrag(sB, wn * 32 + fn * 16 + l15, cb);
#pragma unroll
                for (int fm = 0; fm < 4; fm++)
                    acc[fm][fn] = __builtin_amdgcn_mfma_f32_16x16x32_bf16(a[fm], b, acc[fm][fn], 0, 0, 0);
            }
        }
        barrier_sync();
    }

#pragma unroll
    for (int fm = 0; fm < 4; fm++) {
#pragma unroll
        for (int fn = 0; fn < 2; fn++) {
#pragma unroll
            for (int j = 0; j < 4; j++) {
                int mloc = wm * 64 + fm * 16 + lh * 4 + j;
                int g = m0 + mloc;
                if (g < cnt) {
                    float v = acc[fm][fn][j] * wtLds[mloc];
                    int n = n0 + wn * 32 + fn * 16 + l15;
                    atomicAdd(&out[(size_t)tokLds[mloc] * HD + n], v);
                }
            }
        }
    }
}

// --- launch --------------------------------------------------------------

extern "C" void kernel_launch(void* const* d_in, const int* in_sizes, int n_in,
                              void* d_out, int out_size, void* d_ws, size_t ws_size,
                              hipStream_t stream) {
    const float* hs = (const float*)d_in[0];
    const int* tki = (const int*)d_in[1];
    const float* tkw = (const float*)d_in[2];
    const float* gup = (const float*)d_in[3];
    const float* dnp = (const float*)d_in[4];
    float* out = (float*)d_out;

    char* p = (char*)d_ws;
    int* counts = (int*)p;      p += 256;
    float* combine = (float*)p; p += (size_t)T_TOK * NE * 4;
    int* tok = (int*)p;         p += (size_t)NE * T_TOK * 4;
    float* wts = (float*)p;     p += (size_t)NE * T_TOK * 4;
    __bf16* Xb = (__bf16*)p;    p += (size_t)T_TOK * HD * 2;
    __bf16* act = (__bf16*)p;   // NE*T_TOK*ID*2 = 88MB

    hipMemsetAsync(counts, 0, 256, stream);
    hipMemsetAsync(d_out, 0, (size_t)T_TOK * HD * 4, stream);
    k_combine<<<T_TOK / 256, 256, 0, stream>>>(tki, tkw, combine);
    k_lists<<<T_TOK / 256, 256, 0, stream>>>(combine, counts, tok, wts);
    k_cvt<<<(T_TOK * HD / 8) / 256, 256, 0, stream>>>(hs, Xb);
    k_gemm1<<<dim3(T_TOK / BM, ID / BN, NE), 256, 0, stream>>>(Xb, gup, counts, tok, act);
    k_gemm2<<<dim3(T_TOK / BM, HD / BN, NE), 256, 0, stream>>>(act, dnp, counts, tok, wts, out);
}

// Round 3
// 459.680 us; speedup vs baseline: 2.3573x; 2.3573x over previous
//
#include <hip/hip_runtime.h>
#include <hip/hip_bf16.h>
#include <cstdint>

#define T_TOK 2048
#define HD 2048
#define ID 1408
#define NE 16
#define TOPK 6

#define BM 256
#define BN 64
#define BK 64

typedef __bf16 bf16x8 __attribute__((ext_vector_type(8)));
typedef float f32x4 __attribute__((ext_vector_type(4)));

typedef const __attribute__((address_space(1))) void* gas1_t;
typedef __attribute__((address_space(3))) void* las3_t;
#define GLDS16(g, l) __builtin_amdgcn_global_load_lds((gas1_t)(g), (las3_t)(l), 16, 0, 0)

// --- small kernels -----------------------------------------------------

__global__ void k_combine(const int* __restrict__ idx, const float* __restrict__ w,
                          float* __restrict__ combine) {
    int t = blockIdx.x * blockDim.x + threadIdx.x;
    if (t >= T_TOK) return;
    int ie[TOPK];
    float fw[TOPK];
#pragma unroll
    for (int k = 0; k < TOPK; k++) { ie[k] = idx[t * TOPK + k]; fw[k] = w[t * TOPK + k]; }
#pragma unroll
    for (int e = 0; e < NE; e++) {
        float s = 0.f;
#pragma unroll
        for (int k = 0; k < TOPK; k++) if (ie[k] == e) s += fw[k];
        combine[t * NE + e] = s;
    }
}

__global__ void k_lists(const float* __restrict__ combine, int* __restrict__ counts,
                        int* __restrict__ tok, float* __restrict__ wts) {
    int t = blockIdx.x * blockDim.x + threadIdx.x;
    if (t >= T_TOK) return;
    for (int e = 0; e < NE; e++) {
        float c = combine[t * NE + e];
        if (c != 0.0f) {
            int p = atomicAdd(&counts[e], 1);
            tok[e * T_TOK + p] = t;
            wts[e * T_TOK + p] = c;
        }
    }
}

__global__ void k_cvt(const float* __restrict__ x, __bf16* __restrict__ xb) {
    int i = (blockIdx.x * 256 + threadIdx.x) * 8;
    float4 a = *(const float4*)(x + i);
    float4 b = *(const float4*)(x + i + 4);
    bf16x8 o;
    o[0] = (__bf16)a.x; o[1] = (__bf16)a.y; o[2] = (__bf16)a.z; o[3] = (__bf16)a.w;
    o[4] = (__bf16)b.x; o[5] = (__bf16)b.y; o[6] = (__bf16)b.z; o[7] = (__bf16)b.w;
    *(bf16x8*)(xb + i) = o;
}

// --- LDS helpers -------------------------------------------------------

__device__ __forceinline__ int swz(int row, int cb) {
    // rows are 128B; XOR-swizzle bits 4..6 by row&7 (Guideline 4)
    return row * 128 + (cb ^ ((row & 7) << 4));
}

__device__ __forceinline__ bf16x8 ldfrag(const __bf16* base, int row, int cb) {
    return *(const bf16x8*)((const char*)base + swz(row, cb));
}

// stage 8 fp32 -> 8 bf16 into LDS (one swizzled 16B store)
__device__ __forceinline__ void stage8(const float* __restrict__ src, char* lds,
                                       int row, int cb) {
    float4 f0 = ((const float4*)src)[0];
    float4 f1 = ((const float4*)src)[1];
    bf16x8 o;
    o[0] = (__bf16)f0.x; o[1] = (__bf16)f0.y; o[2] = (__bf16)f0.z; o[3] = (__bf16)f0.w;
    o[4] = (__bf16)f1.x; o[5] = (__bf16)f1.y; o[6] = (__bf16)f1.z; o[7] = (__bf16)f1.w;
    *(bf16x8*)(lds + swz(row, cb)) = o;
}

// --- GEMM1: act = silu(X@Gg^T) * (X@Gu^T)  ------------------------------
// grid.x = e*22 + n  (same (n,e) group => same id mod 8 => same XCD for all m)
// grid.y = m

__global__ __launch_bounds__(512, 4) void k_gemm1(
    const __bf16* __restrict__ Xb, const float* __restrict__ gup,
    const int* __restrict__ counts, const int* __restrict__ tok,
    __bf16* __restrict__ act) {
    int x = blockIdx.x;
    int e = x / 22;
    int n0 = (x % 22) * BN;
    int cnt = counts[e];
    int m0 = blockIdx.y * BM;
    if (m0 >= cnt) return;

    __shared__ __align__(16) __bf16 sA[BM * BK];
    __shared__ __align__(16) __bf16 sBg[BN * BK];
    __shared__ __align__(16) __bf16 sBu[BN * BK];

    int tid = threadIdx.x;
    int lane = tid & 63;
    int wid = tid >> 6;

    // A staging: wave w owns rows [32w, 32w+32). Linear LDS dest via glds;
    // per-lane global source column pre-swizzled so swizzled reads decode it.
    const __bf16* pA[4];
    int csw = ((lane & 7) ^ ((lane >> 3) & 7)) * 8;
#pragma unroll
    for (int j = 0; j < 4; j++) {
        int r = 32 * wid + 8 * j + (lane >> 3);
        int g = m0 + r;
        if (g >= cnt) g = cnt - 1;
        pA[j] = Xb + (size_t)tok[e * T_TOK + g] * HD + csw;
    }

    // B staging roles: 64 rows x 8 chunks of 8 floats
    int br = tid >> 3, bc = tid & 7;
    const float* gbase = gup + (size_t)e * (2 * ID) * HD;
    const float* bgSrc = gbase + (size_t)(n0 + br) * HD + bc * 8;
    const float* buSrc = gbase + (size_t)(ID + n0 + br) * HD + bc * 8;

    int wm = wid >> 1, wn = wid & 1;           // 4x2 waves over 256x64
    int l15 = lane & 15, lh = lane >> 4;

    f32x4 accg[4][2] = {};
    f32x4 accu[4][2] = {};

    for (int k0 = 0; k0 < HD; k0 += BK) {
        __syncthreads();
#pragma unroll
        for (int j = 0; j < 4; j++)
            GLDS16(pA[j] + k0, &sA[(32 * wid + 8 * j) * BK]);
        stage8(bgSrc + k0, (char*)sBg, br, bc * 16);
        stage8(buSrc + k0, (char*)sBu, br, bc * 16);
        __syncthreads();
#pragma unroll
        for (int kk = 0; kk < 2; kk++) {
            int cb = kk * 64 + lh * 16;
            bf16x8 a[4];
#pragma unroll
            for (int fm = 0; fm < 4; fm++)
                a[fm] = ldfrag(sA, wm * 64 + fm * 16 + l15, cb);
#pragma unroll
            for (int fn = 0; fn < 2; fn++) {
                bf16x8 bg = ldfrag(sBg, wn * 32 + fn * 16 + l15, cb);
                bf16x8 bu = ldfrag(sBu, wn * 32 + fn * 16 + l15, cb);
#pragma unroll
                for (int fm = 0; fm < 4; fm++) {
                    accg[fm][fn] = __builtin_amdgcn_mfma_f32_16x16x32_bf16(a[fm], bg, accg[fm][fn], 0, 0, 0);
                    accu[fm][fn] = __builtin_amdgcn_mfma_f32_16x16x32_bf16(a[fm], bu, accu[fm][fn], 0, 0, 0);
                }
            }
        }
    }

    // epilogue: silu(gate)*up -> act (bf16)
#pragma unroll
    for (int fm = 0; fm < 4; fm++) {
#pragma unroll
        for (int fn = 0; fn < 2; fn++) {
#pragma unroll
            for (int j = 0; j < 4; j++) {
                int mloc = wm * 64 + fm * 16 + lh * 4 + j;
                int g = m0 + mloc;
                if (g < cnt) {
                    float gv = accg[fm][fn][j];
                    float uv = accu[fm][fn][j];
                    float sv = gv * (1.0f / (1.0f + __expf(-gv)));
                    int n = n0 + wn * 32 + fn * 16 + l15;
                    act[((size_t)e * T_TOK + g) * ID + n] = (__bf16)(sv * uv);
                }
            }
        }
    }
}

// --- GEMM2: out[tok] += (act @ Dn^T) * wt  (fp32 atomic scatter) --------
// grid.x = e*32 + n (512 = 64*8 => same (n,e) group same XCD); grid.y = m

__global__ __launch_bounds__(512, 6) void k_gemm2(
    const __bf16* __restrict__ act, const float* __restrict__ dn,
    const int* __restrict__ counts, const int* __restrict__ tok,
    const float* __restrict__ wts, float* __restrict__ out) {
    int x = blockIdx.x;
    int e = x >> 5;
    int n0 = (x & 31) * BN;
    int cnt = counts[e];
    int m0 = blockIdx.y * BM;
    if (m0 >= cnt) return;

    __shared__ __align__(16) __bf16 sA[BM * BK];
    __shared__ __align__(16) __bf16 sB[BN * BK];
    __shared__ int tokLds[BM];
    __shared__ float wtLds[BM];

    int tid = threadIdx.x;
    if (tid < BM) {
        int g = m0 + tid;
        bool v = g < cnt;
        tokLds[tid] = v ? tok[e * T_TOK + g] : 0;
        wtLds[tid] = v ? wts[e * T_TOK + g] : 0.f;
    }

    int lane = tid & 63;
    int wid = tid >> 6;

    const __bf16* pA[4];
    int csw = ((lane & 7) ^ ((lane >> 3) & 7)) * 8;
#pragma unroll
    for (int j = 0; j < 4; j++) {
        int r = 32 * wid + 8 * j + (lane >> 3);
        pA[j] = act + ((size_t)e * T_TOK + m0 + r) * ID + csw;
    }

    int br = tid >> 3, bc = tid & 7;
    const float* bSrc = dn + (size_t)e * HD * ID + (size_t)(n0 + br) * ID + bc * 8;

    int wm = wid >> 1, wn = wid & 1;
    int l15 = lane & 15, lh = lane >> 4;

    f32x4 acc[4][2] = {};

    for (int k0 = 0; k0 < ID; k0 += BK) {
        __syncthreads();
#pragma unroll
        for (int j = 0; j < 4; j++)
            GLDS16(pA[j] + k0, &sA[(32 * wid + 8 * j) * BK]);
        stage8(bSrc + k0, (char*)sB, br, bc * 16);
        __syncthreads();
#pragma unroll
        for (int kk = 0; kk < 2; kk++) {
            int cb = kk * 64 + lh * 16;
            bf16x8 a[4];
#pragma unroll
            for (int fm = 0; fm < 4; fm++)
                a[fm] = ldfrag(sA, wm * 64 + fm * 16 + l15, cb);
#pragma unroll
            for (int fn = 0; fn < 2; fn++) {
                bf16x8 b = ldfrag(sB, wn * 32 + fn * 16 + l15, cb);
#pragma unroll
                for (int fm = 0; fm < 4; fm++)
                    acc[fm][fn] = __builtin_amdgcn_mfma_f32_16x16x32_bf16(a[fm], b, acc[fm][fn], 0, 0, 0);
            }
        }
    }

#pragma unroll
    for (int fm = 0; fm < 4; fm++) {
#pragma unroll
        for (int fn = 0; fn < 2; fn++) {
#pragma unroll
            for (int j = 0; j < 4; j++) {
                int mloc = wm * 64 + fm * 16 + lh * 4 + j;
                int g = m0 + mloc;
                if (g < cnt) {
                    float v = acc[fm][fn][j] * wtLds[mloc];
                    int n = n0 + wn * 32 + fn * 16 + l15;
                    atomicAdd(&out[(size_t)tokLds[mloc] * HD + n], v);
                }
            }
        }
    }
}

// --- launch --------------------------------------------------------------

extern "C" void kernel_launch(void* const* d_in, const int* in_sizes, int n_in,
                              void* d_out, int out_size, void* d_ws, size_t ws_size,
                              hipStream_t stream) {
    const float* hs = (const float*)d_in[0];
    const int* tki = (const int*)d_in[1];
    const float* tkw = (const float*)d_in[2];
    const float* gup = (const float*)d_in[3];
    const float* dnp = (const float*)d_in[4];
    float* out = (float*)d_out;

    char* p = (char*)d_ws;
    int* counts = (int*)p;      p += 256;
    float* combine = (float*)p; p += (size_t)T_TOK * NE * 4;
    int* tok = (int*)p;         p += (size_t)NE * T_TOK * 4;
    float* wts = (float*)p;     p += (size_t)NE * T_TOK * 4;
    __bf16* Xb = (__bf16*)p;    p += (size_t)T_TOK * HD * 2;
    __bf16* act = (__bf16*)p;   // NE*T_TOK*ID*2 = 92MB

    hipMemsetAsync(counts, 0, 256, stream);
    hipMemsetAsync(d_out, 0, (size_t)T_TOK * HD * 4, stream);
    k_combine<<<T_TOK / 256, 256, 0, stream>>>(tki, tkw, combine);
    k_lists<<<T_TOK / 256, 256, 0, stream>>>(combine, counts, tok, wts);
    k_cvt<<<(T_TOK * HD / 8) / 256, 256, 0, stream>>>(hs, Xb);
    k_gemm1<<<dim3(22 * NE, T_TOK / BM), 512, 0, stream>>>(Xb, gup, counts, tok, act);
    k_gemm2<<<dim3(32 * NE, T_TOK / BM), 512, 0, stream>>>(act, dnp, counts, tok, wts, out);
}